// Round 2
// baseline (354.188 us; speedup 1.0000x reference)
//
#include <hip/hip_runtime.h>
#include <hip/hip_bf16.h>

typedef short bf16x8 __attribute__((ext_vector_type(8)));
typedef float f32x4 __attribute__((ext_vector_type(4)));

#define AS1 __attribute__((address_space(1)))
#define AS3 __attribute__((address_space(3)))

constexpr int CB = 512;    // channels
constexpr int NB = 2048;   // sequence length
constexpr int BB = 8;      // batch

// ---------------- weights: wq,wk -> hi/lo planes [1024][512]; wv -> bf16; bq,bk -> bqk f32
__global__ void convert_weights(const float* __restrict__ wq, const float* __restrict__ wk,
                                const float* __restrict__ wv, const float* __restrict__ bq,
                                const float* __restrict__ bk,
                                __hip_bfloat16* __restrict__ wqk_h, __hip_bfloat16* __restrict__ wqk_l,
                                __hip_bfloat16* __restrict__ wvb, float* __restrict__ bqk) {
  int i = blockIdx.x * 256 + threadIdx.x;   // grid covers 512*512 exactly
  if (i < CB * CB) {
    float q = wq[i], k = wk[i];
    __hip_bfloat16 qh = __float2bfloat16(q), kh = __float2bfloat16(k);
    wqk_h[i] = qh;
    wqk_l[i] = __float2bfloat16(q - __bfloat162float(qh));
    wqk_h[CB * CB + i] = kh;
    wqk_l[CB * CB + i] = __float2bfloat16(k - __bfloat162float(kh));
    wvb[i] = __float2bfloat16(wv[i]);
  }
  if (i < CB) { bqk[i] = bq[i]; bqk[CB + i] = bk[i]; }
}

// ---------------- x [B][C][N] fp32 -> xbT hi/lo [B][N][C] bf16 (tiled transpose + split)
__global__ void transpose_x(const float* __restrict__ x,
                            __hip_bfloat16* __restrict__ oh, __hip_bfloat16* __restrict__ ol) {
  __shared__ float tile[32][33];
  int b = blockIdx.z, c0 = blockIdx.y * 32, n0 = blockIdx.x * 32;
  int tx = threadIdx.x, ty = threadIdx.y;          // block (32, 8)
  const float* xb = x + (size_t)b * CB * NB;
#pragma unroll
  for (int r = 0; r < 4; r++)
    tile[ty + 8 * r][tx] = xb[(size_t)(c0 + ty + 8 * r) * NB + n0 + tx];
  __syncthreads();
  size_t base = (size_t)b * NB * CB;
#pragma unroll
  for (int r = 0; r < 4; r++) {
    float v = tile[tx][ty + 8 * r];
    __hip_bfloat16 h = __float2bfloat16(v);
    size_t idx = base + (size_t)(n0 + ty + 8 * r) * CB + c0 + tx;
    oh[idx] = h;
    ol[idx] = __float2bfloat16(v - __bfloat162float(h));
  }
}

// ---------------- GEMM-NT:  D[M][N] = Arow[M][K] * Brow[N][K]^T
// 128x128 tile, BK=32, 4 waves (2x2, 64x64 each), global_load_lds staging.
// SPLIT: 1 -> A,B have hi/lo planes, 3 MFMAs (AhBh + AhBl + AlBh)
// BIAS: 0 none, 1 bias[col], 2 bias[row]
// EPI: 0 f32 store; 1 bf16 store; 2 f32 store + residual R(f32); 3 bf16 hi/lo planes (D,D2)
template <int BIAS, int EPI, int SPLIT>
__global__ __launch_bounds__(256) void gemm_nt(
    const __hip_bfloat16* __restrict__ Ah, const __hip_bfloat16* __restrict__ Al, int lda, long sA,
    const __hip_bfloat16* __restrict__ Bh, const __hip_bfloat16* __restrict__ Bl, int ldb, long sB,
    void* __restrict__ D, void* __restrict__ D2, int ldd, long sD,
    const float* __restrict__ bias,
    const float* __restrict__ R, int ldr, long sR,
    int K) {
  constexpr int TSZ = 128 * 32;
  __shared__ alignas(16) __hip_bfloat16 sm[(SPLIT ? 4 : 2) * TSZ];
  __hip_bfloat16* Ash = sm;
  __hip_bfloat16* Bsh = sm + TSZ;
  __hip_bfloat16* Asl = sm + 2 * TSZ;  // used only if SPLIT
  __hip_bfloat16* Bsl = sm + 3 * TSZ;

  const int t = threadIdx.x;
  const int z = blockIdx.z;
  const __hip_bfloat16* Ab = Ah + (size_t)z * sA + (size_t)(blockIdx.y * 128) * lda;
  const __hip_bfloat16* Bb = Bh + (size_t)z * sB + (size_t)(blockIdx.x * 128) * ldb;
  const __hip_bfloat16* Abl = SPLIT ? Al + (size_t)z * sA + (size_t)(blockIdx.y * 128) * lda : nullptr;
  const __hip_bfloat16* Bbl = SPLIT ? Bl + (size_t)z * sB + (size_t)(blockIdx.x * 128) * ldb : nullptr;
  const int wid = t >> 6, l15 = t & 15, hi = (t >> 4) & 3;
  const int wr = wid >> 1, wc = wid & 1;
  const int lineA = t >> 2, eoff = (t & 3) * 8;

  f32x4 acc[4][4] = {};

  for (int kt = 0; kt < K; kt += 32) {
    __syncthreads();
#pragma unroll
    for (int p = 0; p < 2; p++) {
      size_t goA = (size_t)(p * 64 + lineA) * lda + kt + eoff;
      size_t goB = (size_t)(p * 64 + lineA) * ldb + kt + eoff;
      int lo = p * 2048 + t * 8;
      __builtin_amdgcn_global_load_lds((const AS1 void*)(Ab + goA), (AS3 void*)(Ash + lo), 16, 0, 0);
      __builtin_amdgcn_global_load_lds((const AS1 void*)(Bb + goB), (AS3 void*)(Bsh + lo), 16, 0, 0);
      if (SPLIT) {
        __builtin_amdgcn_global_load_lds((const AS1 void*)(Abl + goA), (AS3 void*)(Asl + lo), 16, 0, 0);
        __builtin_amdgcn_global_load_lds((const AS1 void*)(Bbl + goB), (AS3 void*)(Bsl + lo), 16, 0, 0);
      }
    }
    __syncthreads();
    bf16x8 afh[4], bfh[4], afl[4], bfl[4];
#pragma unroll
    for (int f = 0; f < 4; f++) {
      int ao = (wr * 64 + f * 16 + l15) * 32 + hi * 8;
      int bo = (wc * 64 + f * 16 + l15) * 32 + hi * 8;
      afh[f] = *(const bf16x8*)(Ash + ao);
      bfh[f] = *(const bf16x8*)(Bsh + bo);
      if (SPLIT) { afl[f] = *(const bf16x8*)(Asl + ao); bfl[f] = *(const bf16x8*)(Bsl + bo); }
    }
#pragma unroll
    for (int fm = 0; fm < 4; fm++)
#pragma unroll
      for (int fn = 0; fn < 4; fn++) {
        acc[fm][fn] = __builtin_amdgcn_mfma_f32_16x16x32_bf16(afh[fm], bfh[fn], acc[fm][fn], 0, 0, 0);
        if (SPLIT) {
          acc[fm][fn] = __builtin_amdgcn_mfma_f32_16x16x32_bf16(afh[fm], bfl[fn], acc[fm][fn], 0, 0, 0);
          acc[fm][fn] = __builtin_amdgcn_mfma_f32_16x16x32_bf16(afl[fm], bfh[fn], acc[fm][fn], 0, 0, 0);
        }
      }
  }

  const int row0 = blockIdx.y * 128 + wr * 64;
  const int col0 = blockIdx.x * 128 + wc * 64;
#pragma unroll
  for (int fm = 0; fm < 4; fm++) {
    int rowb = row0 + fm * 16 + hi * 4;
#pragma unroll
    for (int fn = 0; fn < 4; fn++) {
      int col = col0 + fn * 16 + l15;
      float bc = (BIAS == 1) ? bias[col] : 0.0f;
#pragma unroll
      for (int r = 0; r < 4; r++) {
        float val = acc[fm][fn][r] + bc;
        if (BIAS == 2) val += bias[rowb + r];
        size_t di = (size_t)(rowb + r) * ldd + col;
        if (EPI == 0) {
          ((float*)D)[(size_t)z * sD + di] = val;
        } else if (EPI == 1) {
          ((__hip_bfloat16*)D)[(size_t)z * sD + di] = __float2bfloat16(val);
        } else if (EPI == 2) {
          val += R[(size_t)z * sR + (size_t)(rowb + r) * ldr + col];
          ((float*)D)[(size_t)z * sD + di] = val;
        } else {  // EPI == 3: hi/lo planes
          __hip_bfloat16 h = __float2bfloat16(val);
          ((__hip_bfloat16*)D)[(size_t)z * sD + di] = h;
          ((__hip_bfloat16*)D2)[(size_t)z * sD + di] = __float2bfloat16(val - __bfloat162float(h));
        }
      }
    }
  }
}

// ---------------- row softmax over S fp32 [rows][2048]; writes P bf16 in-place at row base
struct alignas(16) Bf16x8S { __hip_bfloat16 h[8]; };

__global__ __launch_bounds__(256) void softmax_rows(float* __restrict__ S) {
  float* row = S + (size_t)blockIdx.x * NB;
  int t = threadIdx.x;
  float4 v0 = ((const float4*)row)[t * 2];
  float4 v1 = ((const float4*)row)[t * 2 + 1];
  float vals[8] = {v0.x, v0.y, v0.z, v0.w, v1.x, v1.y, v1.z, v1.w};
  float m = vals[0];
#pragma unroll
  for (int i = 1; i < 8; i++) m = fmaxf(m, vals[i]);
#pragma unroll
  for (int off = 32; off; off >>= 1) m = fmaxf(m, __shfl_xor(m, off));
  __shared__ float redm[4], reds[4];
  if ((t & 63) == 0) redm[t >> 6] = m;
  __syncthreads();
  m = fmaxf(fmaxf(redm[0], redm[1]), fmaxf(redm[2], redm[3]));
  float e[8], s = 0.0f;
#pragma unroll
  for (int i = 0; i < 8; i++) { e[i] = __expf(vals[i] - m); s += e[i]; }
#pragma unroll
  for (int off = 32; off; off >>= 1) s += __shfl_xor(s, off);
  if ((t & 63) == 0) reds[t >> 6] = s;
  __syncthreads();
  s = reds[0] + reds[1] + reds[2] + reds[3];
  float inv = 1.0f / s;
  Bf16x8S ob;
#pragma unroll
  for (int i = 0; i < 8; i++) ob.h[i] = __float2bfloat16(e[i] * inv);
  // all reads of this row happened before the first __syncthreads; safe in-place overlay
  *reinterpret_cast<Bf16x8S*>(reinterpret_cast<char*>(row) + t * 16) = ob;
}

// ---------------- launcher
extern "C" void kernel_launch(void* const* d_in, const int* in_sizes, int n_in,
                              void* d_out, int out_size, void* d_ws, size_t ws_size,
                              hipStream_t stream) {
  const float* x  = (const float*)d_in[0];
  const float* wq = (const float*)d_in[1];
  const float* bq = (const float*)d_in[2];
  const float* wk = (const float*)d_in[3];
  const float* bk = (const float*)d_in[4];
  const float* wv = (const float*)d_in[5];
  const float* bv = (const float*)d_in[6];
  float* out = (float*)d_out;   // fp32 output

  const size_t MB = 1u << 20;
  if (ws_size < 147 * MB) return;

  char* ws = (char*)d_ws;
  // S region [0,64MB) doubles as xbT hi/lo while computing q,k,v (xbT dead before S written)
  float*          S      = (float*)(ws + 0);                  // [4][N][N] f32   64 MB (chunked)
  __hip_bfloat16* xbT_h  = (__hip_bfloat16*)(ws + 0);         // [B][N][C]       16 MB
  __hip_bfloat16* xbT_l  = (__hip_bfloat16*)(ws + 16 * MB);   // [B][N][C]       16 MB
  __hip_bfloat16* v      = (__hip_bfloat16*)(ws + 64 * MB);   // [B][C][N]       16 MB
  __hip_bfloat16* qkT_h  = (__hip_bfloat16*)(ws + 80 * MB);   // [B][N][1024]    32 MB
  __hip_bfloat16* qkT_l  = (__hip_bfloat16*)(ws + 112 * MB);  // [B][N][1024]    32 MB
  __hip_bfloat16* wqk_h  = (__hip_bfloat16*)(ws + 144 * MB);  // [1024][512]      1 MB
  __hip_bfloat16* wqk_l  = (__hip_bfloat16*)(ws + 145 * MB);  // [1024][512]      1 MB
  __hip_bfloat16* wvb    = (__hip_bfloat16*)(ws + 146 * MB);  // [512][512]     0.5 MB
  float*          bqk    = (float*)(ws + 146 * MB + 512 * 1024); // [1024]        4 KB

  convert_weights<<<1024, 256, 0, stream>>>(wq, wk, wv, bq, bk, wqk_h, wqk_l, wvb, bqk);
  transpose_x<<<dim3(64, 16, 8), dim3(32, 8), 0, stream>>>(x, xbT_h, xbT_l);

  // qkT[b][n][o] = sum_c xbT[b][n][c]*wqk[o][c] + bqk[o]   (split precision, hi/lo output)
  gemm_nt<1, 3, 1><<<dim3(8, 16, 8), 256, 0, stream>>>(
      xbT_h, xbT_l, CB, (long)NB * CB, wqk_h, wqk_l, CB, 0,
      qkT_h, qkT_l, 1024, (long)NB * 1024, bqk, nullptr, 0, 0, CB);

  // v[b][c][n] = sum_cin wv[c][cin]*x[b][cin][n] + bv[c]   (plain bf16)
  gemm_nt<2, 1, 0><<<dim3(16, 4, 8), 256, 0, stream>>>(
      wvb, nullptr, CB, 0, xbT_h, nullptr, CB, (long)NB * CB,
      v, nullptr, NB, (long)CB * NB, bv, nullptr, 0, 0, CB);

  // two 4-batch chunks: S -> softmax -> PV, reusing the 64MB S buffer
  for (int c = 0; c < 2; c++) {
    size_t qoff = (size_t)c * 4 * NB * 1024;
    // S[z][i][j] = sum_o qT[i][o] * kT[j][o]   (split precision, fp32 out)
    gemm_nt<0, 0, 1><<<dim3(16, 16, 4), 256, 0, stream>>>(
        qkT_h + qoff, qkT_l + qoff, 1024, (long)NB * 1024,
        qkT_h + qoff + 512, qkT_l + qoff + 512, 1024, (long)NB * 1024,
        S, nullptr, NB, (long)NB * NB, nullptr, nullptr, 0, 0, CB);

    softmax_rows<<<4 * NB, 256, 0, stream>>>(S);

    // out[z][ch][i] = sum_j v[z][ch][j] * P[z][i][j] + x[z][ch][i]   (P bf16 overlay, ld=4096)
    size_t ooff = (size_t)c * 4 * CB * NB;
    gemm_nt<0, 2, 0><<<dim3(16, 4, 4), 256, 0, stream>>>(
        v + (size_t)c * 4 * CB * NB, nullptr, NB, (long)CB * NB,
        (const __hip_bfloat16*)S, nullptr, 2 * NB, (long)NB * 2 * NB,
        out + ooff, nullptr, NB, (long)CB * NB, nullptr,
        x + ooff, NB, (long)CB * NB, NB);
  }
}

// Round 3
// 347.567 us; speedup vs baseline: 1.0190x; 1.0190x over previous
//
#include <hip/hip_runtime.h>
#include <hip/hip_bf16.h>

typedef short bf16x8 __attribute__((ext_vector_type(8)));
typedef float f32x4 __attribute__((ext_vector_type(4)));

#define AS1 __attribute__((address_space(1)))
#define AS3 __attribute__((address_space(3)))

constexpr int CB = 512;    // channels
constexpr int NB = 2048;   // sequence length
constexpr int BB = 8;      // batch

__device__ inline float b2f(short s) {
  unsigned u = ((unsigned)(unsigned short)s) << 16;
  float f; __builtin_memcpy(&f, &u, 4); return f;
}

// ---------------- wv -> bf16
__global__ void convert_wv(const float* __restrict__ wv, __hip_bfloat16* __restrict__ wvb) {
  int i = blockIdx.x * 256 + threadIdx.x;
  if (i < CB * CB) wvb[i] = __float2bfloat16(wv[i]);
}

// ---------------- G[c][d] = sum_o wq[o][c]*wk[o][d], fp32 accum, split hi/lo bf16 out
__global__ __launch_bounds__(256) void compute_G(const float* __restrict__ wq,
                                                 const float* __restrict__ wk,
                                                 __hip_bfloat16* __restrict__ Gh,
                                                 __hip_bfloat16* __restrict__ Gl) {
  __shared__ float aq[32][65];
  __shared__ float ak[32][65];
  int c0 = blockIdx.y * 64, d0 = blockIdx.x * 64;
  int t = threadIdx.x;
  int tc = t & 15, td = t >> 4;
  float acc[4][4] = {};
  for (int o0 = 0; o0 < CB; o0 += 32) {
    __syncthreads();
    int r = t >> 3, cc = (t & 7) * 8;
#pragma unroll
    for (int i = 0; i < 8; i++) {
      aq[r][cc + i] = wq[(size_t)(o0 + r) * CB + c0 + cc + i];
      ak[r][cc + i] = wk[(size_t)(o0 + r) * CB + d0 + cc + i];
    }
    __syncthreads();
#pragma unroll 8
    for (int o = 0; o < 32; o++)
#pragma unroll
      for (int i = 0; i < 4; i++)
#pragma unroll
        for (int j = 0; j < 4; j++)
          acc[i][j] += aq[o][tc * 4 + i] * ak[o][td * 4 + j];
  }
#pragma unroll
  for (int i = 0; i < 4; i++)
#pragma unroll
    for (int j = 0; j < 4; j++) {
      int c = c0 + tc * 4 + i, d = d0 + td * 4 + j;
      float v = acc[i][j];
      __hip_bfloat16 h = __float2bfloat16(v);
      Gh[(size_t)c * CB + d] = h;
      Gl[(size_t)c * CB + d] = __float2bfloat16(v - __bfloat162float(h));
    }
}

// ---------------- u[d] = sum_o bq[o]*wk[o][d]
__global__ void compute_u(const float* __restrict__ wk, const float* __restrict__ bq,
                          float* __restrict__ u) {
  int d = blockIdx.x * 256 + threadIdx.x;
  if (d >= CB) return;
  float s = 0.0f;
  for (int o = 0; o < CB; o++) s += bq[o] * wk[(size_t)o * CB + d];
  u[d] = s;
}

// ---------------- ubias[row] = sum_c u[c] * x[row][c]  (x = xbT hi+lo), row in [0, B*N)
__global__ __launch_bounds__(256) void compute_ubias(const __hip_bfloat16* __restrict__ xh,
                                                     const __hip_bfloat16* __restrict__ xl,
                                                     const float* __restrict__ u,
                                                     float* __restrict__ ub) {
  __shared__ float us[CB];
  for (int i = threadIdx.x; i < CB; i += 256) us[i] = u[i];
  __syncthreads();
  int row = blockIdx.x * 4 + (threadIdx.x >> 6);
  int lane = threadIdx.x & 63;
  bf16x8 vh = *(const bf16x8*)(xh + (size_t)row * CB + lane * 8);
  bf16x8 vl = *(const bf16x8*)(xl + (size_t)row * CB + lane * 8);
  float s = 0.0f;
#pragma unroll
  for (int i = 0; i < 8; i++) s += us[lane * 8 + i] * (b2f(vh[i]) + b2f(vl[i]));
#pragma unroll
  for (int off = 32; off; off >>= 1) s += __shfl_xor(s, off);
  if (lane == 0) ub[row] = s;
}

// ---------------- x [B][C][N] fp32 -> xbT hi/lo [B][N][C] bf16 (tiled transpose + split)
__global__ void transpose_x(const float* __restrict__ x,
                            __hip_bfloat16* __restrict__ oh, __hip_bfloat16* __restrict__ ol) {
  __shared__ float tile[32][33];
  int b = blockIdx.z, c0 = blockIdx.y * 32, n0 = blockIdx.x * 32;
  int tx = threadIdx.x, ty = threadIdx.y;          // block (32, 8)
  const float* xb = x + (size_t)b * CB * NB;
#pragma unroll
  for (int r = 0; r < 4; r++)
    tile[ty + 8 * r][tx] = xb[(size_t)(c0 + ty + 8 * r) * NB + n0 + tx];
  __syncthreads();
  size_t base = (size_t)b * NB * CB;
#pragma unroll
  for (int r = 0; r < 4; r++) {
    float v = tile[tx][ty + 8 * r];
    __hip_bfloat16 h = __float2bfloat16(v);
    size_t idx = base + (size_t)(n0 + ty + 8 * r) * CB + c0 + tx;
    oh[idx] = h;
    ol[idx] = __float2bfloat16(v - __bfloat162float(h));
  }
}

// ---------------- GEMM-NT:  D[M][N] = Arow[M][K] * Brow[N][K]^T
// 128x128 tile, BK=32, 4 waves (2x2), double-buffered LDS with prefetch (T3-minimum).
// SPLIT: A,B hi/lo planes, 3 MFMA passes (AhBh + AhBl + AlBh)
// BIAS: 0 none, 1 batched col-bias f32 (bias[z*sBias+col]), 2 row-bias f32 (bias[z*sBias+row])
// EPI: 0 f32 store; 1 bf16 store; 2 f32 store + residual R(f32); 3 bf16 hi/lo planes (D,D2)
template <int BIAS, int EPI, int SPLIT>
__global__ __launch_bounds__(256) void gemm_nt(
    const __hip_bfloat16* __restrict__ Ah, const __hip_bfloat16* __restrict__ Al, int lda, long sA,
    const __hip_bfloat16* __restrict__ Bh, const __hip_bfloat16* __restrict__ Bl, int ldb, long sB,
    void* __restrict__ D, void* __restrict__ D2, int ldd, long sD,
    const float* __restrict__ bias, long sBias,
    const float* __restrict__ R, int ldr, long sR,
    int K) {
  constexpr int PL = SPLIT ? 4 : 2;
  constexpr int TSZ = 128 * 32;                    // elems per plane tile (8KB)
  __shared__ alignas(16) __hip_bfloat16 sm[2 * PL * TSZ];

  const int t = threadIdx.x;
  const int z = blockIdx.z;
  const __hip_bfloat16* Ab = Ah + (size_t)z * sA + (size_t)(blockIdx.y * 128) * lda;
  const __hip_bfloat16* Bb = Bh + (size_t)z * sB + (size_t)(blockIdx.x * 128) * ldb;
  const __hip_bfloat16* Abl = SPLIT ? Al + (size_t)z * sA + (size_t)(blockIdx.y * 128) * lda : nullptr;
  const __hip_bfloat16* Bbl = SPLIT ? Bl + (size_t)z * sB + (size_t)(blockIdx.x * 128) * ldb : nullptr;
  const int wid = t >> 6, l15 = t & 15, hi = (t >> 4) & 3;
  const int wr = wid >> 1, wc = wid & 1;
  const int lineA = t >> 2, eoff = (t & 3) * 8;

  f32x4 acc[4][4] = {};

  auto stage = [&](int buf, int kt) {
    __hip_bfloat16* base = sm + buf * (PL * TSZ);
#pragma unroll
    for (int p = 0; p < 2; p++) {
      size_t goA = (size_t)(p * 64 + lineA) * lda + kt * 32 + eoff;
      size_t goB = (size_t)(p * 64 + lineA) * ldb + kt * 32 + eoff;
      int lo = p * 2048 + t * 8;
      __builtin_amdgcn_global_load_lds((const AS1 void*)(Ab + goA), (AS3 void*)(base + lo), 16, 0, 0);
      __builtin_amdgcn_global_load_lds((const AS1 void*)(Bb + goB), (AS3 void*)(base + TSZ + lo), 16, 0, 0);
      if (SPLIT) {
        __builtin_amdgcn_global_load_lds((const AS1 void*)(Abl + goA), (AS3 void*)(base + 2 * TSZ + lo), 16, 0, 0);
        __builtin_amdgcn_global_load_lds((const AS1 void*)(Bbl + goB), (AS3 void*)(base + 3 * TSZ + lo), 16, 0, 0);
      }
    }
  };

  const int nt = K >> 5;
  stage(0, 0);
  __syncthreads();                 // drains stage(0); buf0 ready
  int cur = 0;
  for (int kt = 0; kt < nt; kt++) {
    if (kt + 1 < nt) stage(cur ^ 1, kt + 1);   // prefetch next tile
    const __hip_bfloat16* bb = sm + cur * (PL * TSZ);
    bf16x8 afh[4], bfh[4], afl[4], bfl[4];
#pragma unroll
    for (int f = 0; f < 4; f++) {
      int ao = (wr * 64 + f * 16 + l15) * 32 + hi * 8;
      int bo = (wc * 64 + f * 16 + l15) * 32 + hi * 8;
      afh[f] = *(const bf16x8*)(bb + ao);
      bfh[f] = *(const bf16x8*)(bb + TSZ + bo);
      if (SPLIT) { afl[f] = *(const bf16x8*)(bb + 2 * TSZ + ao); bfl[f] = *(const bf16x8*)(bb + 3 * TSZ + bo); }
    }
#pragma unroll
    for (int pass = 0; pass < (SPLIT ? 3 : 1); pass++) {
#pragma unroll
      for (int fm = 0; fm < 4; fm++)
#pragma unroll
        for (int fn = 0; fn < 4; fn++) {
          const bf16x8 a = (pass == 2) ? afl[fm] : afh[fm];
          const bf16x8 b = (pass == 1) ? bfl[fn] : bfh[fn];
          acc[fm][fn] = __builtin_amdgcn_mfma_f32_16x16x32_bf16(a, b, acc[fm][fn], 0, 0, 0);
        }
    }
    __syncthreads();               // drains prefetch + protects buf reuse
    cur ^= 1;
  }

  const int row0 = blockIdx.y * 128 + wr * 64;
  const int col0 = blockIdx.x * 128 + wc * 64;
#pragma unroll
  for (int fm = 0; fm < 4; fm++) {
    int rowb = row0 + fm * 16 + hi * 4;
#pragma unroll
    for (int fn = 0; fn < 4; fn++) {
      int col = col0 + fn * 16 + l15;
      float bc = (BIAS == 1) ? bias[(size_t)z * sBias + col] : 0.0f;
#pragma unroll
      for (int r = 0; r < 4; r++) {
        float val = acc[fm][fn][r] + bc;
        if (BIAS == 2) val += bias[(size_t)z * sBias + rowb + r];
        size_t di = (size_t)(rowb + r) * ldd + col;
        if (EPI == 0) {
          ((float*)D)[(size_t)z * sD + di] = val;
        } else if (EPI == 1) {
          ((__hip_bfloat16*)D)[(size_t)z * sD + di] = __float2bfloat16(val);
        } else if (EPI == 2) {
          val += R[(size_t)z * sR + (size_t)(rowb + r) * ldr + col];
          ((float*)D)[(size_t)z * sD + di] = val;
        } else {
          __hip_bfloat16 h = __float2bfloat16(val);
          ((__hip_bfloat16*)D)[(size_t)z * sD + di] = h;
          ((__hip_bfloat16*)D2)[(size_t)z * sD + di] = __float2bfloat16(val - __bfloat162float(h));
        }
      }
    }
  }
}

// ---------------- row softmax over S fp32 [rows][2048]; writes P bf16 in-place at row base
struct alignas(16) Bf16x8S { __hip_bfloat16 h[8]; };

__global__ __launch_bounds__(256) void softmax_rows(float* __restrict__ S) {
  float* row = S + (size_t)blockIdx.x * NB;
  int t = threadIdx.x;
  float4 v0 = ((const float4*)row)[t * 2];
  float4 v1 = ((const float4*)row)[t * 2 + 1];
  float vals[8] = {v0.x, v0.y, v0.z, v0.w, v1.x, v1.y, v1.z, v1.w};
  float m = vals[0];
#pragma unroll
  for (int i = 1; i < 8; i++) m = fmaxf(m, vals[i]);
#pragma unroll
  for (int off = 32; off; off >>= 1) m = fmaxf(m, __shfl_xor(m, off));
  __shared__ float redm[4], reds[4];
  if ((t & 63) == 0) redm[t >> 6] = m;
  __syncthreads();
  m = fmaxf(fmaxf(redm[0], redm[1]), fmaxf(redm[2], redm[3]));
  float e[8], s = 0.0f;
#pragma unroll
  for (int i = 0; i < 8; i++) { e[i] = __expf(vals[i] - m); s += e[i]; }
#pragma unroll
  for (int off = 32; off; off >>= 1) s += __shfl_xor(s, off);
  if ((t & 63) == 0) reds[t >> 6] = s;
  __syncthreads();
  s = reds[0] + reds[1] + reds[2] + reds[3];
  float inv = 1.0f / s;
  Bf16x8S ob;
#pragma unroll
  for (int i = 0; i < 8; i++) ob.h[i] = __float2bfloat16(e[i] * inv);
  *reinterpret_cast<Bf16x8S*>(reinterpret_cast<char*>(row) + t * 16) = ob;
}

// ---------------- launcher
extern "C" void kernel_launch(void* const* d_in, const int* in_sizes, int n_in,
                              void* d_out, int out_size, void* d_ws, size_t ws_size,
                              hipStream_t stream) {
  const float* x  = (const float*)d_in[0];
  const float* wq = (const float*)d_in[1];
  const float* bq = (const float*)d_in[2];
  const float* wk = (const float*)d_in[3];
  const float* wv = (const float*)d_in[5];
  const float* bv = (const float*)d_in[6];
  float* out = (float*)d_out;

  const size_t MB = 1u << 20;
  if (ws_size < 146 * MB) return;

  char* ws = (char*)d_ws;
  __hip_bfloat16* xbT_h = (__hip_bfloat16*)(ws + 0);           // [B][N][C]    16 MB
  __hip_bfloat16* xbT_l = (__hip_bfloat16*)(ws + 16 * MB);     // [B][N][C]    16 MB
  __hip_bfloat16* YT_h  = (__hip_bfloat16*)(ws + 32 * MB);     // [B][N][C]    16 MB
  __hip_bfloat16* YT_l  = (__hip_bfloat16*)(ws + 48 * MB);     // [B][N][C]    16 MB
  __hip_bfloat16* v     = (__hip_bfloat16*)(ws + 64 * MB);     // [B][C][N]    16 MB
  float*          S     = (float*)(ws + 80 * MB);              // [4][N][N]    64 MB (chunked)
  __hip_bfloat16* Gh    = (__hip_bfloat16*)(ws + 144 * MB);    // [C][C]      0.5 MB
  __hip_bfloat16* Gl    = (__hip_bfloat16*)(ws + 144 * MB + 512 * 1024);
  __hip_bfloat16* wvb   = (__hip_bfloat16*)(ws + 145 * MB);    // [C][C]      0.5 MB
  float*          u     = (float*)(ws + 145 * MB + 512 * 1024);   // [C]        2 KB
  float*          ub    = (float*)(ws + 145 * MB + 768 * 1024);   // [B][N]    64 KB

  convert_wv<<<1024, 256, 0, stream>>>(wv, wvb);
  compute_G<<<dim3(8, 8), 256, 0, stream>>>(wq, wk, Gh, Gl);
  compute_u<<<2, 256, 0, stream>>>(wk, bq, u);
  transpose_x<<<dim3(64, 16, 8), dim3(32, 8), 0, stream>>>(x, xbT_h, xbT_l);
  compute_ubias<<<BB * NB / 4, 256, 0, stream>>>(xbT_h, xbT_l, u, ub);

  // YT[b][j][c] = sum_d xbT[b][j][d] * G[c][d]   (split, hi/lo out)
  gemm_nt<0, 3, 1><<<dim3(4, 16, 8), 256, 0, stream>>>(
      xbT_h, xbT_l, CB, (long)NB * CB, Gh, Gl, CB, 0,
      YT_h, YT_l, CB, (long)NB * CB, nullptr, 0, nullptr, 0, 0, CB);

  // v[b][c][n] = sum_cin wv[c][cin]*x[b][cin][n] + bv[c]
  gemm_nt<2, 1, 0><<<dim3(16, 4, 8), 256, 0, stream>>>(
      wvb, nullptr, CB, 0, xbT_h, nullptr, CB, (long)NB * CB,
      v, nullptr, NB, (long)CB * NB, bv, 0, nullptr, 0, 0, CB);

  for (int c = 0; c < 2; c++) {
    size_t xoff = (size_t)c * 4 * NB * CB;
    // S[z][i][j] = sum_c xbT[i][c]*YT[j][c] + ub[z][j]
    gemm_nt<1, 0, 1><<<dim3(16, 16, 4), 256, 0, stream>>>(
        xbT_h + xoff, xbT_l + xoff, CB, (long)NB * CB,
        YT_h + xoff, YT_l + xoff, CB, (long)NB * CB,
        S, nullptr, NB, (long)NB * NB, ub + (size_t)c * 4 * NB, NB, nullptr, 0, 0, CB);

    softmax_rows<<<4 * NB, 256, 0, stream>>>(S);

    size_t ooff = (size_t)c * 4 * CB * NB;
    // out[z][ch][i] = sum_j v[z][ch][j]*P[z][i][j] + x[z][ch][i]
    gemm_nt<0, 2, 0><<<dim3(16, 4, 4), 256, 0, stream>>>(
        v + ooff, nullptr, NB, (long)CB * NB,
        (const __hip_bfloat16*)S, nullptr, 2 * NB, (long)NB * 2 * NB,
        out + ooff, nullptr, NB, (long)CB * NB, nullptr, 0,
        x + ooff, NB, (long)CB * NB, NB);
  }
}